// Round 2
// 377.223 us; speedup vs baseline: 1.0390x; 1.0390x over previous
//
#include <hip/hip_runtime.h>

#define B_      8
#define C_      64
#define T_      32
#define HW_     3136        // 56*56
#define HW4_    784         // HW_/4 (float4 units)
#define NPC_    802816.0    // B_*T_*HW_ per-channel element count
#define EPS_    1e-5
#define CHUNKS_ 7           // ceil(784/128)
#define BLK_    128

// native clang vector type: required by __builtin_nontemporal_* (HIP float4
// is a struct and is rejected). Same 16-byte layout as float4.
typedef float f32x4 __attribute__((ext_vector_type(4)));

// rp[t] = 6*(x[t]-x[t-6]) + 4*(x[t-1]-x[t-5]) + 2*(x[t-2]-x[t-4])
__device__ __forceinline__ float rp_tap(float a0, float a1, float a2,
                                        float a4, float a5, float a6) {
    return 6.f * (a0 - a6) + 4.f * (a1 - a5) + 2.f * (a2 - a4);
}

// ---------------- Pass 1: FIR + per-tile (sum, sumsq) -> ws slots -----------
// Loads stay CACHING on purpose: they populate L3 so pass 2's re-read hits.
__global__ __launch_bounds__(BLK_, 4) void datt_pass1(
    const float* __restrict__ x, double2* __restrict__ part)
{
    const int bc    = blockIdx.y;                  // b*C_ + c
    const int chunk = blockIdx.x;
    const int hw4   = chunk * BLK_ + threadIdx.x;

    float s = 0.f, q = 0.f;
    if (hw4 < HW4_) {
        const float4* xp = (const float4*)(x + (size_t)bc * (T_ * HW_)) + hw4;
        float4 win[7];
#pragma unroll
        for (int k = 0; k < 7; ++k) win[k] = make_float4(0.f, 0.f, 0.f, 0.f);
#pragma unroll
        for (int t = 0; t < T_; ++t) {
            float4 xv = xp[(size_t)t * HW4_];
            win[t % 7] = xv;
            const float4 a1 = win[(t + 6) % 7];
            const float4 a2 = win[(t + 5) % 7];
            const float4 a4 = win[(t + 3) % 7];
            const float4 a5 = win[(t + 2) % 7];
            const float4 a6 = win[(t + 1) % 7];
            float rx = rp_tap(xv.x, a1.x, a2.x, a4.x, a5.x, a6.x);
            float ry = rp_tap(xv.y, a1.y, a2.y, a4.y, a5.y, a6.y);
            float rz = rp_tap(xv.z, a1.z, a2.z, a4.z, a5.z, a6.z);
            float rw = rp_tap(xv.w, a1.w, a2.w, a4.w, a5.w, a6.w);
            s += rx + ry + rz + rw;
            q += rx * rx + ry * ry + rz * rz + rw * rw;
        }
    }
#pragma unroll
    for (int off = 32; off; off >>= 1) {
        s += __shfl_down(s, off);
        q += __shfl_down(q, off);
    }
    __shared__ float ls[2], lq[2];
    const int wid  = threadIdx.x >> 6;
    const int lane = threadIdx.x & 63;
    if (lane == 0) { ls[wid] = s; lq[wid] = q; }
    __syncthreads();
    if (threadIdx.x == 0) {
        const int tile = bc * CHUNKS_ + chunk;
        part[tile] = make_double2((double)(ls[0] + ls[1]),
                                  (double)(lq[0] + lq[1]));
    }
}

// ------- Pass 2: reduce channel stats + FIR + BN + ReLU + gate + write ------
// x loads are last-touch -> non-temporal; out stores are streaming ->
// non-temporal so they never evict x from the Infinity Cache mid-pass.
__global__ __launch_bounds__(BLK_, 4) void datt_pass2(
    const float* __restrict__ x,
    const double2* __restrict__ part,
    const float* __restrict__ gamma,
    const float* __restrict__ beta,
    const float* __restrict__ rpw,
    float* __restrict__ out)
{
    const int bc    = blockIdx.y;
    const int c     = bc & (C_ - 1);
    const int chunk = blockIdx.x;
    const int tid   = threadIdx.x;

    __shared__ float lss[2];   // scale, shift

    // wave 0: reduce the 56 per-tile partials of this channel
    if (tid < 64) {
        double s = 0.0, q = 0.0;
        if (tid < B_ * CHUNKS_) {                   // 56 slots
            const int b  = tid / CHUNKS_;
            const int ch = tid - b * CHUNKS_;
            double2 p = part[(b * C_ + c) * CHUNKS_ + ch];
            s = p.x; q = p.y;
        }
#pragma unroll
        for (int off = 32; off; off >>= 1) {
            s += __shfl_down(s, off);
            q += __shfl_down(q, off);
        }
        if (tid == 0) {
            double mean = s / NPC_;
            double var  = q / NPC_ - mean * mean;
            float rstd  = (float)(1.0 / sqrt(var + EPS_));
            float sc    = gamma[c] * rstd;
            lss[0] = sc;
            lss[1] = beta[c] - (float)mean * sc;
        }
    }
    __syncthreads();

    const int hw4 = chunk * BLK_ + tid;
    if (hw4 >= HW4_) return;

    const float sc = lss[0];
    const float sh = lss[1];
    const float r1 = rpw[1];
    const float A  = rpw[0] + r1;        // out = x * (A + r1*y)

    const f32x4* xp = (const f32x4*)(x   + (size_t)bc * (T_ * HW_)) + hw4;
    f32x4*       op = (f32x4*)      (out + (size_t)bc * (T_ * HW_)) + hw4;

    f32x4 win[7];
#pragma unroll
    for (int k = 0; k < 7; ++k) win[k] = (f32x4)(0.f);
#pragma unroll
    for (int t = 0; t < T_; ++t) {
        f32x4 xv = __builtin_nontemporal_load(&xp[(size_t)t * HW4_]);
        win[t % 7] = xv;
        const f32x4 a1 = win[(t + 6) % 7];
        const f32x4 a2 = win[(t + 5) % 7];
        const f32x4 a4 = win[(t + 3) % 7];
        const f32x4 a5 = win[(t + 2) % 7];
        const f32x4 a6 = win[(t + 1) % 7];
        f32x4 o;
#pragma unroll
        for (int j = 0; j < 4; ++j) {
            float yj = fmaxf(fmaf(rp_tap(xv[j], a1[j], a2[j], a4[j], a5[j], a6[j]),
                                  sc, sh), 0.f);
            o[j] = xv[j] * fmaf(r1, yj, A);
        }
        __builtin_nontemporal_store(o, &op[(size_t)t * HW4_]);
    }
}

extern "C" void kernel_launch(void* const* d_in, const int* in_sizes, int n_in,
                              void* d_out, int out_size, void* d_ws, size_t ws_size,
                              hipStream_t stream) {
    const float* x     = (const float*)d_in[0];
    const float* gamma = (const float*)d_in[1];
    const float* beta  = (const float*)d_in[2];
    const float* rpw   = (const float*)d_in[3];
    // d_in[4] is w == 7, hard-coded.
    float* out = (float*)d_out;

    double2* part = (double2*)d_ws;      // B_*C_*CHUNKS_ = 3584 slots, 57 KB

    dim3 grid(CHUNKS_, B_ * C_);
    datt_pass1<<<grid, BLK_, 0, stream>>>(x, part);
    datt_pass2<<<grid, BLK_, 0, stream>>>(x, part, gamma, beta, rpw, out);
}